// Round 6
// baseline (324.534 us; speedup 1.0000x reference)
//
#include <hip/hip_runtime.h>
#include <hip/hip_bf16.h>
#include <hip/hip_cooperative_groups.h>

namespace cg = cooperative_groups;

// B=128, CIN=3, H=W=32, C1=64, C2=256, NUM_CLASSES=1000
// K_CONV=48, K_FC=12451 >= 48*256 => FC reduces exactly to the 48 selected
// channels' pooled features (non-selected channels are exactly zero).
// Slot order = gate-score rank order; FC sum is order-invariant.
// Single cooperative kernel, 5 phases separated by grid.sync() to kill
// per-kernel launch/boundary overhead (R5 theory: ~80us of boundaries).

#define NSEL 48
#define NCLS 1000

__device__ __forceinline__ unsigned short f2bf(float x) {
  unsigned u = __builtin_bit_cast(unsigned, x);
  u += 0x7fffu + ((u >> 16) & 1u);  // RNE (finite inputs)
  return (unsigned short)(u >> 16);
}

__device__ __forceinline__ void gl_lds16(const void* g, void* l) {
  __builtin_amdgcn_global_load_lds(
      (const __attribute__((address_space(1))) void*)g,
      (__attribute__((address_space(3))) void*)l, 16, 0, 0);
}

using sh8 = __attribute__((ext_vector_type(8))) short;
using f4  = __attribute__((ext_vector_type(4))) float;

__global__ __launch_bounds__(256, 2) void fused(
    const float* __restrict__ x0, const float* __restrict__ w1,
    const float* __restrict__ b1, const float* __restrict__ gate_w,
    const float* __restrict__ w2, const float* __restrict__ b2,
    const float* __restrict__ fc_w, const float* __restrict__ fc_b,
    float* __restrict__ out,
    unsigned short* __restrict__ x1, unsigned short* __restrict__ pooledt,
    float* __restrict__ part2, int* __restrict__ sel,
    unsigned short* __restrict__ w2t, float* __restrict__ b2s,
    float* __restrict__ fcpart) {
  cg::grid_group grid = cg::this_grid();
  __shared__ __align__(16) char smem[41472];
  const int bid = blockIdx.x;  // 0..511
  const int t = threadIdx.x;   // 0..255

  // ================= P1: conv1 + ReLU -> x1 bf16 [b][pix][64ic]; |.| sums ========
  {
    const int b = bid >> 2, quarter = bid & 3;
    const int wv = t >> 6;
    float* xs = (float*)smem;            // 3840 f
    float* wred = (float*)(smem + 15360);  // 256 f
    const int r0 = quarter * 8;

    for (int q = 0; q < 15; ++q) {
      const int id = q * 256 + t;
      const int ic = id / 320;
      const int rem = id - ic * 320;
      const int row = rem >> 5, col = rem & 31;
      const int gr = r0 - 1 + row;
      xs[id] = ((unsigned)gr < 32u)
                   ? x0[((size_t)b * 3 + ic) * 1024 + gr * 32 + col] : 0.f;
    }
    __syncthreads();

    const int lr = t >> 5, pc = t & 31;
    float win[3][3][3];
#pragma unroll
    for (int ic = 0; ic < 3; ++ic)
#pragma unroll
      for (int kr = 0; kr < 3; ++kr)
#pragma unroll
        for (int kc = 0; kc < 3; ++kc) {
          const int cc = pc - 1 + kc;
          win[ic][kr][kc] = ((unsigned)cc < 32u) ? xs[ic * 320 + (lr + kr) * 32 + cc] : 0.f;
        }

    unsigned pk[32];
#pragma unroll
    for (int oc = 0; oc < 64; ++oc) {
      float a = b1[oc];
#pragma unroll
      for (int ic = 0; ic < 3; ++ic)
#pragma unroll
        for (int kr = 0; kr < 3; ++kr)
#pragma unroll
          for (int kc = 0; kc < 3; ++kc)
            a += w1[oc * 27 + ic * 9 + kr * 3 + kc] * win[ic][kr][kc];
      const float v = a > 0.f ? a : 0.f;
      const unsigned bf = f2bf(v);
      if (oc & 1) pk[oc >> 1] |= bf << 16; else pk[oc >> 1] = bf;
      float rs = v;
      for (int off = 32; off > 0; off >>= 1) rs += __shfl_down(rs, off, 64);
      if ((t & 63) == 0) wred[oc * 4 + wv] = rs;
    }

    {
      int4* dst = reinterpret_cast<int4*>(x1) +
                  ((size_t)b * 1024 + (r0 + lr) * 32 + pc) * 8;
      const int4* src = reinterpret_cast<const int4*>(pk);
#pragma unroll
      for (int j2 = 0; j2 < 8; ++j2) dst[j2] = src[j2];
    }
    __syncthreads();
    if (t < 64) {
      const float s = wred[t * 4] + wred[t * 4 + 1] + wred[t * 4 + 2] + wred[t * 4 + 3];
      part2[((size_t)quarter * 64 + t) * 128 + b] = s;
    }
  }

  grid.sync();

  // ================= P2: selection + weight prep (blocks 0..47) ==================
  if (bid < NSEL) {
    const int j = bid;  // slot = rank
    float* red = (float*)smem;             // 64*33 f
    float* sig = (float*)(smem + 8448);    // 64 f
    float* sc  = (float*)(smem + 8704);    // 256 f
    int*  pick = (int*)(smem + 9728);

    // Full reduction of part2 (32768 floats = 8192 float4).
    // f = q*256+t: channel c = (q&7)*8 + (t>>5); col4 = t&31; quarter = q>>3.
    float prt[8];
#pragma unroll
    for (int k = 0; k < 8; ++k) prt[k] = 0.f;
    const float4* pv = reinterpret_cast<const float4*>(part2);
#pragma unroll
    for (int q = 0; q < 32; ++q) {
      const float4 v = pv[q * 256 + t];
      prt[q & 7] += v.x + v.y + v.z + v.w;
    }
#pragma unroll
    for (int k = 0; k < 8; ++k)
      red[(k * 8 + (t >> 5)) * 33 + (t & 31)] = prt[k];
    __syncthreads();
    if (t < 64) {
      float s = 0.f;
      for (int i = 0; i < 32; ++i) s += red[t * 33 + i];
      sig[t] = s * (1.0f / 131072.0f);
    }
    __syncthreads();

    {  // gate logits (softplus monotone -> rank by logits)
      float lg = 0.f;
#pragma unroll 8
      for (int i = 0; i < 64; ++i) lg += gate_w[t * 64 + i] * sig[i];
      sc[t] = lg;
    }
    __syncthreads();

    {  // rank = position in desc sort with index tiebreak (top_k order)
      const float v = sc[t];
      int r = 0;
      for (int i = 0; i < 256; ++i) {
        const float vi = sc[i];
        r += (vi > v) || (vi == v && i < t);
      }
      if (r == j) *pick = t;
      if (j == 0 && r < NSEL) sel[r] = t;
    }
    __syncthreads();

    const int c = *pick;
    if (t == 0) b2s[j] = b2[c];
    for (int id = t; id < 576; id += 256) {
      const float v = w2[(size_t)c * 576 + id];
      const int ic = id / 9;
      const int s = id - ic * 9;
      w2t[((size_t)s * 48 + j) * 64 + ic] = f2bf(v);
    }
  }

  grid.sync();

  // ================= P3: conv2 via 9-shift bf16 MFMA + bias + ReLU + maxpool =====
  {
    const int b = bid >> 2, quarter = bid & 3;
    const int w = t >> 6, l = t & 63;
    const int q4 = l >> 4, ln15 = l & 15;
    short* xt = (short*)smem;  // 20480 shorts

    const int r0 = quarter * 8;

    for (int q = 0; q < 10; ++q) {
      const int S = (w * 10 + q) * 64 + l;
      const int pix = S >> 3, slot = S & 7;
      const int row = pix >> 5, col = pix & 31;
      int gr = r0 - 1 + row;
      gr = gr < 0 ? 0 : (gr > 31 ? 31 : gr);
      const unsigned short* gsrc =
          x1 + ((size_t)(b * 1024 + gr * 32 + col) * 64) + (slot ^ (pix & 7)) * 8;
      gl_lds16((const void*)gsrc, (void*)&xt[(w * 10 + q) * 512]);
    }
    __syncthreads();

    f4 acc[4][3];
    const f4 fz = {0.f, 0.f, 0.f, 0.f};
#pragma unroll
    for (int i = 0; i < 4; ++i)
#pragma unroll
      for (int nt = 0; nt < 3; ++nt) acc[i][nt] = fz;

    const int w4 = w * 4;
    const sh8 zz = {0, 0, 0, 0, 0, 0, 0, 0};

#pragma unroll
    for (int kh = 0; kh < 3; ++kh)
#pragma unroll
      for (int kw = 0; kw < 3; ++kw) {
        const int sh = kh * 3 + kw;
        sh8 bf[3][2];
#pragma unroll
        for (int nt = 0; nt < 3; ++nt)
#pragma unroll
          for (int ks = 0; ks < 2; ++ks)
            bf[nt][ks] = *reinterpret_cast<const sh8*>(
                w2t + ((size_t)(sh * 48 + nt * 16 + ln15) * 64 + ks * 32 + q4 * 8));
#pragma unroll
        for (int i = 0; i < 4; ++i) {
          const int mt = w4 + i;
          const int lsr = (mt >> 1) + kh;
          const int gsr = r0 + lsr - 1;
          if ((unsigned)gsr < 32u) {
            const int w_ = (mt & 1) * 16 + ln15;
            const int cc = w_ + kw - 1;
            const bool cv = (unsigned)cc < 32u;
            int p = lsr * 32 + cc;
            p = p < 0 ? 0 : (p > 319 ? 319 : p);
#pragma unroll
            for (int ks = 0; ks < 2; ++ks) {
              sh8 af = *reinterpret_cast<const sh8*>(
                  &xt[p * 64 + (((ks << 2) | q4) ^ (p & 7)) * 8]);
              af = cv ? af : zz;
              acc[i][0] = __builtin_amdgcn_mfma_f32_16x16x32_bf16(af, bf[0][ks], acc[i][0], 0, 0, 0);
              acc[i][1] = __builtin_amdgcn_mfma_f32_16x16x32_bf16(af, bf[1][ks], acc[i][1], 0, 0, 0);
              acc[i][2] = __builtin_amdgcn_mfma_f32_16x16x32_bf16(af, bf[2][ks], acc[i][2], 0, 0, 0);
            }
          }
        }
      }

    __syncthreads();  // done reading xt; reuse as pooled staging [48 oc][64 p]

    float bias[3];
#pragma unroll
    for (int nt = 0; nt < 3; ++nt) bias[nt] = b2s[nt * 16 + ln15];

    unsigned short* ps = reinterpret_cast<unsigned short*>(xt);
#pragma unroll
    for (int a = 0; a < 2; ++a) {
#pragma unroll
      for (int nt = 0; nt < 3; ++nt) {
        const f4 A = acc[a][nt], Bv = acc[a + 2][nt];
#pragma unroll
        for (int pr = 0; pr < 2; ++pr) {
          float m = fmaxf(fmaxf(A[pr * 2], A[pr * 2 + 1]),
                          fmaxf(Bv[pr * 2], Bv[pr * 2 + 1]));
          m = fmaxf(m + bias[nt], 0.f);
          const int pl = w * 16 + a * 8 + q4 * 2 + pr;
          ps[(nt * 16 + ln15) * 64 + pl] = f2bf(m);
        }
      }
    }
    __syncthreads();

    const int4* psv = reinterpret_cast<const int4*>(xt);
    int4* po = reinterpret_cast<int4*>(pooledt);
    for (int c = t; c < 384; c += 256) {
      const int j = c >> 3, sub = c & 7;
      po[(size_t)(j * 32 + quarter * 8 + sub) * 128 + b] = psv[c];
    }
  }

  grid.sync();

  // ================= P4: FC bf16 MFMA partials. BM=128, BN=32, Ksplit=16 =========
  {
    const int ntile = bid & 31, ks = bid >> 5;
    const int w = t >> 6, l = t & 63;
    short* Ab = (short*)smem;             // [2][8*129*8] = 33024 B
    short* Bb = (short*)(smem + 33024);   // [2][8*33*8]  =  8448 B
    const int ABUF = 8 * 129 * 8, BBUF = 8 * 33 * 8;

    f4 acc00 = {0.f, 0.f, 0.f, 0.f}, acc01 = acc00, acc10 = acc00, acc11 = acc00;

    int ch[3];
#pragma unroll
    for (int i = 0; i < 3; ++i)
      ch[i] = __builtin_amdgcn_readfirstlane(sel[ks * 3 + i]);

    const int n0 = ntile * 32;
    const int nrow = t >> 3, koct = t & 7;
    int ng = n0 + nrow; if (ng > 999) ng = 999;
    const float* wbase = fc_w + (size_t)ng * 65536 + koct * 8;

    const int4* pt = reinterpret_cast<const int4*>(pooledt);
    const int kb0 = ks * 96;

    int4 av[4];
    float4 bv0, bv1;

    {  // stage tile 0
#pragma unroll
      for (int it = 0; it < 4; ++it) {
        const int s = it * 256 + t;
        av[it] = pt[(kb0 + (s >> 7)) * 128 + (s & 127)];
      }
      const float* bp = wbase + ch[0] * 256;
      bv0 = *reinterpret_cast<const float4*>(bp);
      bv1 = *reinterpret_cast<const float4*>(bp + 4);
#pragma unroll
      for (int it = 0; it < 4; ++it) {
        const int s = it * 256 + t;
        *reinterpret_cast<int4*>(&Ab[((s >> 7) * 129 + (s & 127)) * 8]) = av[it];
      }
      int4 bw;
      bw.x = f2bf(bv0.x) | ((unsigned)f2bf(bv0.y) << 16);
      bw.y = f2bf(bv0.z) | ((unsigned)f2bf(bv0.w) << 16);
      bw.z = f2bf(bv1.x) | ((unsigned)f2bf(bv1.y) << 16);
      bw.w = f2bf(bv1.z) | ((unsigned)f2bf(bv1.w) << 16);
      *reinterpret_cast<int4*>(&Bb[(koct * 33 + nrow) * 8]) = bw;
    }
    __syncthreads();

    for (int tt = 0; tt < 12; ++tt) {
      const int cur = tt & 1, nxt = cur ^ 1;
      if (tt < 11) {
        const int tn = tt + 1;
#pragma unroll
        for (int it = 0; it < 4; ++it) {
          const int s = it * 256 + t;
          av[it] = pt[(kb0 + tn * 8 + (s >> 7)) * 128 + (s & 127)];
        }
        const float* bp = wbase + ch[tn >> 2] * 256 + (tn & 3) * 64;
        bv0 = *reinterpret_cast<const float4*>(bp);
        bv1 = *reinterpret_cast<const float4*>(bp + 4);
      }

#pragma unroll
      for (int s2 = 0; s2 < 2; ++s2) {
        const int kg = s2 * 4 + (l >> 4);
        const int m0 = w * 32 + (l & 15);
        sh8 a0 = *reinterpret_cast<const sh8*>(&Ab[cur * ABUF + (kg * 129 + m0) * 8]);
        sh8 a1 = *reinterpret_cast<const sh8*>(&Ab[cur * ABUF + (kg * 129 + m0 + 16) * 8]);
        sh8 b0 = *reinterpret_cast<const sh8*>(&Bb[cur * BBUF + (kg * 33 + (l & 15)) * 8]);
        sh8 b1 = *reinterpret_cast<const sh8*>(&Bb[cur * BBUF + (kg * 33 + 16 + (l & 15)) * 8]);
        acc00 = __builtin_amdgcn_mfma_f32_16x16x32_bf16(a0, b0, acc00, 0, 0, 0);
        acc01 = __builtin_amdgcn_mfma_f32_16x16x32_bf16(a0, b1, acc01, 0, 0, 0);
        acc10 = __builtin_amdgcn_mfma_f32_16x16x32_bf16(a1, b0, acc10, 0, 0, 0);
        acc11 = __builtin_amdgcn_mfma_f32_16x16x32_bf16(a1, b1, acc11, 0, 0, 0);
      }

      if (tt < 11) {
#pragma unroll
        for (int it = 0; it < 4; ++it) {
          const int s = it * 256 + t;
          *reinterpret_cast<int4*>(&Ab[nxt * ABUF + ((s >> 7) * 129 + (s & 127)) * 8]) = av[it];
        }
        int4 bw;
        bw.x = f2bf(bv0.x) | ((unsigned)f2bf(bv0.y) << 16);
        bw.y = f2bf(bv0.z) | ((unsigned)f2bf(bv0.w) << 16);
        bw.z = f2bf(bv1.x) | ((unsigned)f2bf(bv1.y) << 16);
        bw.w = f2bf(bv1.z) | ((unsigned)f2bf(bv1.w) << 16);
        *reinterpret_cast<int4*>(&Bb[nxt * BBUF + (koct * 33 + nrow) * 8]) = bw;
      }
      __syncthreads();
    }

    const int r0 = (l >> 4) * 4;
#pragma unroll
    for (int fm = 0; fm < 2; ++fm)
#pragma unroll
      for (int fn = 0; fn < 2; ++fn)
#pragma unroll
        for (int r = 0; r < 4; ++r) {
          const int m = w * 32 + fm * 16 + r0 + r;
          const int nc = n0 + fn * 16 + (l & 15);
          const f4 a = fm == 0 ? (fn == 0 ? acc00 : acc01) : (fn == 0 ? acc10 : acc11);
          fcpart[(((size_t)ks * 128 + m) << 10) + nc] = a[r];
        }
  }

  grid.sync();

  // ================= P5: reduce K-split partials + bias ==========================
  {
    const int id = bid * 256 + t;
    if (id < 128000) {
      const int b = id / 1000;
      const int n = id - b * 1000;
      float s = fc_b[n];
#pragma unroll
      for (int ks = 0; ks < 16; ++ks)
        s += fcpart[(((size_t)ks * 128 + b) << 10) + n];
      out[id] = s;
    }
  }
}

extern "C" void kernel_launch(void* const* d_in, const int* in_sizes, int n_in,
                              void* d_out, int out_size, void* d_ws, size_t ws_size,
                              hipStream_t stream) {
  (void)in_sizes; (void)n_in; (void)out_size; (void)ws_size;
  const float* x0     = (const float*)d_in[0];
  const float* w1     = (const float*)d_in[1];
  const float* b1     = (const float*)d_in[2];
  const float* gate_w = (const float*)d_in[3];
  const float* w2     = (const float*)d_in[4];
  const float* b2     = (const float*)d_in[5];
  const float* fc_w   = (const float*)d_in[6];
  const float* fc_b   = (const float*)d_in[7];
  float* out = (float*)d_out;

  char* ws = (char*)d_ws;
  unsigned short* x1      = (unsigned short*)(ws);             // 16,777,216 B
  unsigned short* pooledt = (unsigned short*)(ws + 16777216);  //  3,145,728 B
  float*          part2   = (float*)(ws + 19922944);           //    131,072 B
  int*            sel     = (int*)  (ws + 20054016);           //        256 B
  unsigned short* w2t     = (unsigned short*)(ws + 20054272);  //     55,296 B
  float*          b2s     = (float*)(ws + 20109568);           //        768 B
  float*          fcpart  = (float*)(ws + 20110336);           //  8,388,608 B

  void* args[] = {
      (void*)&x0, (void*)&w1, (void*)&b1, (void*)&gate_w, (void*)&w2,
      (void*)&b2, (void*)&fc_w, (void*)&fc_b, (void*)&out,
      (void*)&x1, (void*)&pooledt, (void*)&part2, (void*)&sel,
      (void*)&w2t, (void*)&b2s, (void*)&fcpart};
  hipLaunchCooperativeKernel((void*)fused, dim3(512), dim3(256), args, 0, stream);
}

// Round 8
// 163.381 us; speedup vs baseline: 1.9864x; 1.9864x over previous
//
#include <hip/hip_runtime.h>
#include <hip/hip_bf16.h>

// B=128, CIN=3, H=W=32, C1=64, C2=256, NUM_CLASSES=1000
// K_CONV=48, K_FC=12451 >= 48*256 => FC reduces exactly to the 48 selected
// channels' pooled features (non-selected channels are exactly zero).
// Slot order = gate-score rank order; FC sum is order-invariant.
// 4 kernels (boundary ~10-15us each; grid.sync measured ~75us -> avoided).

#define NSEL 48
#define NCLS 1000

__device__ __forceinline__ unsigned short f2bf(float x) {
  unsigned u = __builtin_bit_cast(unsigned, x);
  u += 0x7fffu + ((u >> 16) & 1u);  // RNE (finite inputs)
  return (unsigned short)(u >> 16);
}

__device__ __forceinline__ void gl_lds16(const void* g, void* l) {
  __builtin_amdgcn_global_load_lds(
      (const __attribute__((address_space(1))) void*)g,
      (__attribute__((address_space(3))) void*)l, 16, 0, 0);
}

using sh8 = __attribute__((ext_vector_type(8))) short;
using f4  = __attribute__((ext_vector_type(4))) float;

// ---------------- K1: conv1 + ReLU -> x1 bf16 [b][pix][64ic]; |.| partial sums ----
__global__ __launch_bounds__(256) void k1_conv1(
    const float* __restrict__ x0, const float* __restrict__ w1,
    const float* __restrict__ b1, unsigned short* __restrict__ x1,
    float* __restrict__ part2) {
  const int b = blockIdx.x, quarter = blockIdx.y;
  const int t = threadIdx.x;
  const int wv = t >> 6;
  __shared__ float xs[3 * 320];   // 3 ic x 10 rows x 32 cols
  __shared__ float wred[64 * 4];
  const int r0 = quarter * 8;

  for (int q = 0; q < 15; ++q) {  // 3840 floats
    const int id = q * 256 + t;
    const int ic = id / 320;
    const int rem = id - ic * 320;
    const int row = rem >> 5, col = rem & 31;
    const int gr = r0 - 1 + row;
    xs[id] = ((unsigned)gr < 32u)
                 ? x0[((size_t)b * 3 + ic) * 1024 + gr * 32 + col] : 0.f;
  }
  __syncthreads();

  const int lr = t >> 5, pc = t & 31;
  float win[3][3][3];
#pragma unroll
  for (int ic = 0; ic < 3; ++ic)
#pragma unroll
    for (int kr = 0; kr < 3; ++kr)
#pragma unroll
      for (int kc = 0; kc < 3; ++kc) {
        const int cc = pc - 1 + kc;
        win[ic][kr][kc] = ((unsigned)cc < 32u) ? xs[ic * 320 + (lr + kr) * 32 + cc] : 0.f;
      }

  unsigned pk[32];
#pragma unroll
  for (int oc = 0; oc < 64; ++oc) {
    float a = b1[oc];
#pragma unroll
    for (int ic = 0; ic < 3; ++ic)
#pragma unroll
      for (int kr = 0; kr < 3; ++kr)
#pragma unroll
        for (int kc = 0; kc < 3; ++kc)
          a += w1[oc * 27 + ic * 9 + kr * 3 + kc] * win[ic][kr][kc];
    const float v = a > 0.f ? a : 0.f;
    const unsigned bf = f2bf(v);
    if (oc & 1) pk[oc >> 1] |= bf << 16; else pk[oc >> 1] = bf;
    float rs = v;
    for (int off = 32; off > 0; off >>= 1) rs += __shfl_down(rs, off, 64);
    if ((t & 63) == 0) wred[oc * 4 + wv] = rs;
  }

  {
    int4* dst = reinterpret_cast<int4*>(x1) +
                ((size_t)b * 1024 + (r0 + lr) * 32 + pc) * 8;
    const int4* src = reinterpret_cast<const int4*>(pk);
#pragma unroll
    for (int j2 = 0; j2 < 8; ++j2) dst[j2] = src[j2];
  }
  __syncthreads();
  if (t < 64) {
    const float s = wred[t * 4] + wred[t * 4 + 1] + wred[t * 4 + 2] + wred[t * 4 + 3];
    part2[((size_t)quarter * 64 + t) * 128 + b] = s;
  }
}

// ---------------- K2: selection (redundant per block) + weight prep (block j) -----
__global__ __launch_bounds__(256) void k2_selprep(
    const float* __restrict__ part2, const float* __restrict__ gate_w,
    const float* __restrict__ w2, const float* __restrict__ b2,
    int* __restrict__ sel, unsigned short* __restrict__ w2t,
    float* __restrict__ b2s) {
  const int t = threadIdx.x;
  const int j = blockIdx.x;  // slot = rank
  __shared__ float red[64 * 33];
  __shared__ float sig[64];
  __shared__ float sc[256];
  __shared__ int pick;

  // Full reduction of part2 (32768 floats = 8192 float4).
  // f = q*256+t: channel c = (q&7)*8 + (t>>5); col4 = t&31; quarter = q>>3.
  float prt[8];
#pragma unroll
  for (int k = 0; k < 8; ++k) prt[k] = 0.f;
  const float4* pv = reinterpret_cast<const float4*>(part2);
#pragma unroll
  for (int q = 0; q < 32; ++q) {
    const float4 v = pv[q * 256 + t];
    prt[q & 7] += v.x + v.y + v.z + v.w;
  }
#pragma unroll
  for (int k = 0; k < 8; ++k)
    red[(k * 8 + (t >> 5)) * 33 + (t & 31)] = prt[k];
  __syncthreads();
  if (t < 64) {
    float s = 0.f;
    for (int i = 0; i < 32; ++i) s += red[t * 33 + i];
    sig[t] = s * (1.0f / 131072.0f);
  }
  __syncthreads();

  {  // gate logits (softplus monotone -> rank by logits)
    float lg = 0.f;
#pragma unroll 8
    for (int i = 0; i < 64; ++i) lg += gate_w[t * 64 + i] * sig[i];
    sc[t] = lg;
  }
  __syncthreads();

  {  // rank = position in desc sort with index tiebreak (top_k order)
    const float v = sc[t];
    int r = 0;
    for (int i = 0; i < 256; ++i) {
      const float vi = sc[i];
      r += (vi > v) || (vi == v && i < t);
    }
    if (r == j) pick = t;
    if (j == 0 && r < NSEL) sel[r] = t;
  }
  __syncthreads();

  const int c = pick;
  if (t == 0) b2s[j] = b2[c];
  for (int id = t; id < 576; id += 256) {
    const float v = w2[(size_t)c * 576 + id];
    const int ic = id / 9;
    const int s = id - ic * 9;
    w2t[((size_t)s * 48 + j) * 64 + ic] = f2bf(v);
  }
}

// ---------------- K3: conv2 via 9-shift bf16 MFMA + bias + ReLU + maxpool ---------
__global__ __launch_bounds__(256) void k3_conv2(
    const unsigned short* __restrict__ x1, const unsigned short* __restrict__ w2t,
    const float* __restrict__ b2s, unsigned short* __restrict__ pooledt,
    int* __restrict__ cnt) {
  const int b = blockIdx.x, quarter = blockIdx.y;
  const int t = threadIdx.x;
  const int w = t >> 6, l = t & 63;
  const int q4 = l >> 4, ln15 = l & 15;
  __shared__ short xt[20480];  // 10 rows x 32 cols x 64 ic bf16, 16B-slot swizzled

  // re-zero k4's completion counters each call (stream-ordered before k4)
  if (b == 0 && quarter == 0 && t < 32) cnt[t] = 0;

  const int r0 = quarter * 8;

  for (int q = 0; q < 10; ++q) {
    const int S = (w * 10 + q) * 64 + l;
    const int pix = S >> 3, slot = S & 7;
    const int row = pix >> 5, col = pix & 31;
    int gr = r0 - 1 + row;
    gr = gr < 0 ? 0 : (gr > 31 ? 31 : gr);
    const unsigned short* gsrc =
        x1 + ((size_t)(b * 1024 + gr * 32 + col) * 64) + (slot ^ (pix & 7)) * 8;
    gl_lds16((const void*)gsrc, (void*)&xt[(w * 10 + q) * 512]);
  }
  __syncthreads();

  f4 acc[4][3];
  const f4 fz = {0.f, 0.f, 0.f, 0.f};
#pragma unroll
  for (int i = 0; i < 4; ++i)
#pragma unroll
    for (int nt = 0; nt < 3; ++nt) acc[i][nt] = fz;

  const int w4 = w * 4;
  const sh8 zz = {0, 0, 0, 0, 0, 0, 0, 0};

#pragma unroll
  for (int kh = 0; kh < 3; ++kh)
#pragma unroll
    for (int kw = 0; kw < 3; ++kw) {
      const int sh = kh * 3 + kw;
      sh8 bf[3][2];
#pragma unroll
      for (int nt = 0; nt < 3; ++nt)
#pragma unroll
        for (int ks = 0; ks < 2; ++ks)
          bf[nt][ks] = *reinterpret_cast<const sh8*>(
              w2t + ((size_t)(sh * 48 + nt * 16 + ln15) * 64 + ks * 32 + q4 * 8));
#pragma unroll
      for (int i = 0; i < 4; ++i) {
        const int mt = w4 + i;
        const int lsr = (mt >> 1) + kh;
        const int gsr = r0 + lsr - 1;
        if ((unsigned)gsr < 32u) {
          const int w_ = (mt & 1) * 16 + ln15;
          const int cc = w_ + kw - 1;
          const bool cv = (unsigned)cc < 32u;
          int p = lsr * 32 + cc;
          p = p < 0 ? 0 : (p > 319 ? 319 : p);
#pragma unroll
          for (int ks = 0; ks < 2; ++ks) {
            sh8 af = *reinterpret_cast<const sh8*>(
                &xt[p * 64 + (((ks << 2) | q4) ^ (p & 7)) * 8]);
            af = cv ? af : zz;
            acc[i][0] = __builtin_amdgcn_mfma_f32_16x16x32_bf16(af, bf[0][ks], acc[i][0], 0, 0, 0);
            acc[i][1] = __builtin_amdgcn_mfma_f32_16x16x32_bf16(af, bf[1][ks], acc[i][1], 0, 0, 0);
            acc[i][2] = __builtin_amdgcn_mfma_f32_16x16x32_bf16(af, bf[2][ks], acc[i][2], 0, 0, 0);
          }
        }
      }
    }

  __syncthreads();  // done reading xt; reuse as pooled staging [48 oc][64 p]

  float bias[3];
#pragma unroll
  for (int nt = 0; nt < 3; ++nt) bias[nt] = b2s[nt * 16 + ln15];

  unsigned short* ps = reinterpret_cast<unsigned short*>(xt);
#pragma unroll
  for (int a = 0; a < 2; ++a) {
#pragma unroll
    for (int nt = 0; nt < 3; ++nt) {
      const f4 A = acc[a][nt], Bv = acc[a + 2][nt];
#pragma unroll
      for (int pr = 0; pr < 2; ++pr) {
        float m = fmaxf(fmaxf(A[pr * 2], A[pr * 2 + 1]),
                        fmaxf(Bv[pr * 2], Bv[pr * 2 + 1]));
        m = fmaxf(m + bias[nt], 0.f);
        const int pl = w * 16 + a * 8 + q4 * 2 + pr;
        ps[(nt * 16 + ln15) * 64 + pl] = f2bf(m);
      }
    }
  }
  __syncthreads();

  const int4* psv = reinterpret_cast<const int4*>(xt);
  int4* po = reinterpret_cast<int4*>(pooledt);
  for (int c = t; c < 384; c += 256) {
    const int j = c >> 3, sub = c & 7;
    po[(size_t)(j * 32 + quarter * 8 + sub) * 128 + b] = psv[c];
  }
}

// ---------------- K4: FC bf16 MFMA partials + threadfence-fused reduction ---------
// grid (32 ntile, 16 ks). Last-finishing block per ntile reduces + writes out.
__global__ __launch_bounds__(256) void k4_fc(
    const unsigned short* __restrict__ pooledt, const float* __restrict__ fc_w,
    const int* __restrict__ sel, const float* __restrict__ fc_b,
    float* __restrict__ fcpart, int* __restrict__ cnt,
    float* __restrict__ out) {
  const int ntile = blockIdx.x;  // 0..31
  const int ks = blockIdx.y;     // 0..15 (K chunk = 768 = 3 channels)
  const int t = threadIdx.x;
  const int w = t >> 6, l = t & 63;

  __shared__ short Ab[2][8 * 129 * 8];  // [ko][m pad129][8]
  __shared__ short Bb[2][8 * 33 * 8];   // [ko][n pad33][8]
  __shared__ int done;

  f4 acc00 = {0.f, 0.f, 0.f, 0.f}, acc01 = acc00, acc10 = acc00, acc11 = acc00;

  int ch[3];
#pragma unroll
  for (int i = 0; i < 3; ++i)
    ch[i] = __builtin_amdgcn_readfirstlane(sel[ks * 3 + i]);

  const int n0 = ntile * 32;
  const int nrow = t >> 3, koct = t & 7;
  int ng = n0 + nrow; if (ng > 999) ng = 999;  // clamp (cols >=1000 skipped below)
  const float* wbase = fc_w + (size_t)ng * 65536 + koct * 8;

  const int4* pt = reinterpret_cast<const int4*>(pooledt);
  const int kb0 = ks * 96;

  int4 av[4];
  float4 bv0, bv1;

  {  // stage tile 0
#pragma unroll
    for (int it = 0; it < 4; ++it) {
      const int s = it * 256 + t;
      av[it] = pt[(kb0 + (s >> 7)) * 128 + (s & 127)];
    }
    const float* bp = wbase + ch[0] * 256;
    bv0 = *reinterpret_cast<const float4*>(bp);
    bv1 = *reinterpret_cast<const float4*>(bp + 4);
#pragma unroll
    for (int it = 0; it < 4; ++it) {
      const int s = it * 256 + t;
      *reinterpret_cast<int4*>(&Ab[0][((s >> 7) * 129 + (s & 127)) * 8]) = av[it];
    }
    int4 bw;
    bw.x = f2bf(bv0.x) | ((unsigned)f2bf(bv0.y) << 16);
    bw.y = f2bf(bv0.z) | ((unsigned)f2bf(bv0.w) << 16);
    bw.z = f2bf(bv1.x) | ((unsigned)f2bf(bv1.y) << 16);
    bw.w = f2bf(bv1.z) | ((unsigned)f2bf(bv1.w) << 16);
    *reinterpret_cast<int4*>(&Bb[0][(koct * 33 + nrow) * 8]) = bw;
  }
  __syncthreads();

  for (int tt = 0; tt < 12; ++tt) {
    const int cur = tt & 1, nxt = cur ^ 1;
    if (tt < 11) {
      const int tn = tt + 1;
#pragma unroll
      for (int it = 0; it < 4; ++it) {
        const int s = it * 256 + t;
        av[it] = pt[(kb0 + tn * 8 + (s >> 7)) * 128 + (s & 127)];
      }
      const float* bp = wbase + ch[tn >> 2] * 256 + (tn & 3) * 64;
      bv0 = *reinterpret_cast<const float4*>(bp);
      bv1 = *reinterpret_cast<const float4*>(bp + 4);
    }

#pragma unroll
    for (int s2 = 0; s2 < 2; ++s2) {
      const int kg = s2 * 4 + (l >> 4);
      const int m0 = w * 32 + (l & 15);
      sh8 a0 = *reinterpret_cast<const sh8*>(&Ab[cur][(kg * 129 + m0) * 8]);
      sh8 a1 = *reinterpret_cast<const sh8*>(&Ab[cur][(kg * 129 + m0 + 16) * 8]);
      sh8 b0 = *reinterpret_cast<const sh8*>(&Bb[cur][(kg * 33 + (l & 15)) * 8]);
      sh8 b1 = *reinterpret_cast<const sh8*>(&Bb[cur][(kg * 33 + 16 + (l & 15)) * 8]);
      acc00 = __builtin_amdgcn_mfma_f32_16x16x32_bf16(a0, b0, acc00, 0, 0, 0);
      acc01 = __builtin_amdgcn_mfma_f32_16x16x32_bf16(a0, b1, acc01, 0, 0, 0);
      acc10 = __builtin_amdgcn_mfma_f32_16x16x32_bf16(a1, b0, acc10, 0, 0, 0);
      acc11 = __builtin_amdgcn_mfma_f32_16x16x32_bf16(a1, b1, acc11, 0, 0, 0);
    }

    if (tt < 11) {
#pragma unroll
      for (int it = 0; it < 4; ++it) {
        const int s = it * 256 + t;
        *reinterpret_cast<int4*>(&Ab[nxt][((s >> 7) * 129 + (s & 127)) * 8]) = av[it];
      }
      int4 bw;
      bw.x = f2bf(bv0.x) | ((unsigned)f2bf(bv0.y) << 16);
      bw.y = f2bf(bv0.z) | ((unsigned)f2bf(bv0.w) << 16);
      bw.z = f2bf(bv1.x) | ((unsigned)f2bf(bv1.y) << 16);
      bw.w = f2bf(bv1.z) | ((unsigned)f2bf(bv1.w) << 16);
      *reinterpret_cast<int4*>(&Bb[nxt][(koct * 33 + nrow) * 8]) = bw;
    }
    __syncthreads();
  }

  {  // write this block's partial slice
    const int r0 = (l >> 4) * 4;
#pragma unroll
    for (int fm = 0; fm < 2; ++fm)
#pragma unroll
      for (int fn = 0; fn < 2; ++fn)
#pragma unroll
        for (int r = 0; r < 4; ++r) {
          const int m = w * 32 + fm * 16 + r0 + r;
          const int nc = n0 + fn * 16 + (l & 15);
          const f4 a = fm == 0 ? (fn == 0 ? acc00 : acc01) : (fn == 0 ? acc10 : acc11);
          fcpart[(((size_t)ks * 128 + m) << 10) + nc] = a[r];
        }
  }

  // threadfence reduction: 16th finisher per ntile sums partials + bias -> out
  __threadfence();
  if (t == 0) done = atomicAdd(&cnt[ntile], 1);
  __syncthreads();
  if (done == 15) {
    __threadfence();
#pragma unroll
    for (int it = 0; it < 16; ++it) {
      const int idx = it * 256 + t;       // 0..4095
      const int m = idx >> 5, nc = idx & 31;
      const int n = n0 + nc;
      if (n < NCLS) {
        float s = fc_b[n];
#pragma unroll
        for (int kr = 0; kr < 16; ++kr)
          s += fcpart[(((size_t)kr * 128 + m) << 10) + n];
        out[m * NCLS + n] = s;
      }
    }
  }
}

extern "C" void kernel_launch(void* const* d_in, const int* in_sizes, int n_in,
                              void* d_out, int out_size, void* d_ws, size_t ws_size,
                              hipStream_t stream) {
  (void)in_sizes; (void)n_in; (void)out_size; (void)ws_size;
  const float* x0     = (const float*)d_in[0];
  const float* w1     = (const float*)d_in[1];
  const float* b1     = (const float*)d_in[2];
  const float* gate_w = (const float*)d_in[3];
  const float* w2     = (const float*)d_in[4];
  const float* b2     = (const float*)d_in[5];
  const float* fc_w   = (const float*)d_in[6];
  const float* fc_b   = (const float*)d_in[7];
  float* out = (float*)d_out;

  char* ws = (char*)d_ws;
  unsigned short* x1      = (unsigned short*)(ws);             // 16,777,216 B
  unsigned short* pooledt = (unsigned short*)(ws + 16777216);  //  3,145,728 B
  float*          part2   = (float*)(ws + 19922944);           //    131,072 B
  int*            sel     = (int*)  (ws + 20054016);           //        256 B
  unsigned short* w2t     = (unsigned short*)(ws + 20054272);  //     55,296 B
  float*          b2s     = (float*)(ws + 20109568);           //        768 B
  int*            cnt     = (int*)  (ws + 20110336);           //        128 B
  float*          fcpart  = (float*)(ws + 20110464);           //  8,388,608 B

  hipLaunchKernelGGL(k1_conv1, dim3(128, 4), dim3(256), 0, stream, x0, w1, b1, x1, part2);
  hipLaunchKernelGGL(k2_selprep, dim3(48), dim3(256), 0, stream, part2, gate_w, w2, b2, sel, w2t, b2s);
  hipLaunchKernelGGL(k3_conv2, dim3(128, 4), dim3(256), 0, stream, x1, w2t, b2s, pooledt, cnt);
  hipLaunchKernelGGL(k4_fc, dim3(32, 16), dim3(256), 0, stream, pooledt, fc_w, sel, fc_b, fcpart, cnt, out);
}